// Round 1
// 2364.651 us; speedup vs baseline: 5.2370x; 5.2370x over previous
//
#include <hip/hip_runtime.h>

#define NU 32

static constexpr int cN1 = 250000, cN2 = 500000, cN3 = 1000000, cN4 = 1500000;
static constexpr int cNR = 50000, cER = 300000;

// tanh(x) = 1 - 2/(exp(2x)+1), via v_exp_f32 + v_rcp_f32
__device__ __forceinline__ float fast_tanh(float x) {
    float e = __builtin_amdgcn_exp2f(x * 2.88539008177792681f); // exp(2x)
    return 1.0f - 2.0f * __builtin_amdgcn_rcpf(e + 1.0f);
}

// One node's MLP: concat(ROWS x 32 inputs) @ W1[ROWS*32,32] + b1 -> tanh -> @ W2[32,32] + b2
// Weights are wave-uniform -> scalar loads broadcast into v_fma.
template<int ROWS>
__device__ __forceinline__ void mlp_node(const float* const (&in)[ROWS],
    const float* __restrict__ W1, const float* __restrict__ b1,
    const float* __restrict__ W2, const float* __restrict__ b2,
    float* outp)
{
    float hid[NU];
    #pragma unroll
    for (int j = 0; j < NU; j++) hid[j] = b1[j];
    #pragma unroll
    for (int p = 0; p < ROWS; p++) {
        const float4* v4 = (const float4*)in[p];
        const float* wb = W1 + p * NU * NU;
        #pragma unroll
        for (int q = 0; q < 8; q++) {
            float4 v = v4[q];
            float xs[4] = {v.x, v.y, v.z, v.w};
            #pragma unroll
            for (int r = 0; r < 4; r++) {
                float x = xs[r];
                const float* w = wb + (q * 4 + r) * NU;
                #pragma unroll
                for (int j = 0; j < NU; j++) hid[j] = fmaf(x, w[j], hid[j]);
            }
        }
    }
    float o[NU];
    #pragma unroll
    for (int c = 0; c < NU; c++) o[c] = b2[c];
    #pragma unroll
    for (int j = 0; j < NU; j++) {
        float t = fast_tanh(hid[j]);
        const float* w = W2 + j * NU;
        #pragma unroll
        for (int c = 0; c < NU; c++) o[c] = fmaf(t, w[c], o[c]);
    }
    float4* o4 = (float4*)outp;
    #pragma unroll
    for (int q = 0; q < 8; q++)
        o4[q] = make_float4(o[4*q], o[4*q+1], o[4*q+2], o[4*q+3]);
}

// MLP where second input block (rows 32..63 of W1) comes from a register array.
__device__ __forceinline__ void mlp2_reg(const float* __restrict__ selfp,
    const float (&x2)[NU],
    const float* __restrict__ W1, const float* __restrict__ b1,
    const float* __restrict__ W2, const float* __restrict__ b2,
    float* __restrict__ outp)
{
    float hid[NU];
    #pragma unroll
    for (int j = 0; j < NU; j++) hid[j] = b1[j];
    const float4* v4 = (const float4*)selfp;
    #pragma unroll
    for (int q = 0; q < 8; q++) {
        float4 v = v4[q];
        float xs[4] = {v.x, v.y, v.z, v.w};
        #pragma unroll
        for (int r = 0; r < 4; r++) {
            const float* w = W1 + (q * 4 + r) * NU;
            float x = xs[r];
            #pragma unroll
            for (int j = 0; j < NU; j++) hid[j] = fmaf(x, w[j], hid[j]);
        }
    }
    #pragma unroll
    for (int k = 0; k < NU; k++) {
        const float* w = W1 + (NU + k) * NU;
        float x = x2[k];
        #pragma unroll
        for (int j = 0; j < NU; j++) hid[j] = fmaf(x, w[j], hid[j]);
    }
    float o[NU];
    #pragma unroll
    for (int c = 0; c < NU; c++) o[c] = b2[c];
    #pragma unroll
    for (int j = 0; j < NU; j++) {
        float t = fast_tanh(hid[j]);
        const float* w = W2 + j * NU;
        #pragma unroll
        for (int c = 0; c < NU; c++) o[c] = fmaf(t, w[c], o[c]);
    }
    float4* o4 = (float4*)outp;
    #pragma unroll
    for (int q = 0; q < 8; q++)
        o4[q] = make_float4(o[4*q], o[4*q+1], o[4*q+2], o[4*q+3]);
}

// Up pass: m = [self_row | prev[i0] | prev[i1]] -> MLP -> out
__global__ __launch_bounds__(256) void up_kernel(
    const float* __restrict__ self, const float* __restrict__ prev,
    const int* __restrict__ i0, const int* __restrict__ i1,
    const float* __restrict__ W1, const float* __restrict__ b1,
    const float* __restrict__ W2, const float* __restrict__ b2,
    float* __restrict__ out, int N)
{
    int n = blockIdx.x * 256 + threadIdx.x;
    if (n >= N) return;
    int g0 = i0[n], g1 = i1[n];
    const float* in[3] = { self + (size_t)n * NU,
                           prev + (size_t)g0 * NU,
                           prev + (size_t)g1 * NU };
    mlp_node<3>(in, W1, b1, W2, b2, out + (size_t)n * NU);
}

// ---------------- CSR build: histogram -> scan -> fill ----------------

__global__ __launch_bounds__(256) void hist2_kernel(
    const int* __restrict__ i0, const int* __restrict__ i1, int* cnt, int N)
{
    int n = blockIdx.x * 256 + threadIdx.x;
    if (n >= N) return;
    atomicAdd(&cnt[i0[n]], 1);
    atomicAdd(&cnt[i1[n]], 1);
}

__global__ __launch_bounds__(256) void hist1_kernel(
    const int* __restrict__ idx, int* cnt, int E)
{
    int e = blockIdx.x * 256 + threadIdx.x;
    if (e >= E) return;
    atomicAdd(&cnt[idx[e]], 1);
}

// Block scans 1024 elements (256 thr x 4). Writes per-block-exclusive prefix
// into excl[] and block total into bsums[blockIdx.x].
__global__ __launch_bounds__(256) void scan1_kernel(
    const int* __restrict__ cnt, int* __restrict__ excl,
    int* __restrict__ bsums, int M)
{
    __shared__ int sm[256];
    int t = threadIdx.x;
    int base = blockIdx.x * 1024 + t * 4;
    int c0 = (base + 0 < M) ? cnt[base + 0] : 0;
    int c1 = (base + 1 < M) ? cnt[base + 1] : 0;
    int c2 = (base + 2 < M) ? cnt[base + 2] : 0;
    int c3 = (base + 3 < M) ? cnt[base + 3] : 0;
    int s = c0 + c1 + c2 + c3;
    sm[t] = s;
    __syncthreads();
    for (int off = 1; off < 256; off <<= 1) {
        int v = (t >= off) ? sm[t - off] : 0;
        __syncthreads();
        sm[t] += v;
        __syncthreads();
    }
    int e0 = sm[t] - s;  // exclusive for this thread's 4 elements
    if (base + 0 < M) excl[base + 0] = e0;
    if (base + 1 < M) excl[base + 1] = e0 + c0;
    if (base + 2 < M) excl[base + 2] = e0 + c0 + c1;
    if (base + 3 < M) excl[base + 3] = e0 + c0 + c1 + c2;
    if (t == 255) bsums[blockIdx.x] = sm[255];
}

// Single block: exclusive scan of NB (<=1024) block sums, in place.
__global__ __launch_bounds__(1024) void scan2_kernel(int* bsums, int NB)
{
    __shared__ int sm[1024];
    int t = threadIdx.x;
    int v = (t < NB) ? bsums[t] : 0;
    sm[t] = v;
    __syncthreads();
    for (int off = 1; off < 1024; off <<= 1) {
        int u = (t >= off) ? sm[t - off] : 0;
        __syncthreads();
        sm[t] += u;
        __syncthreads();
    }
    if (t < NB) bsums[t] = sm[t] - v;
}

// start[i] += bsums[block]; cur[i] = start[i] (cursor init for fill)
__global__ __launch_bounds__(256) void scan3_kernel(
    int* __restrict__ start, int* __restrict__ cur,
    const int* __restrict__ bsums, int M)
{
    int i = blockIdx.x * 256 + threadIdx.x;
    if (i >= M) return;
    int s = start[i] + bsums[i >> 10];
    start[i] = s;
    cur[i] = s;
}

__global__ __launch_bounds__(256) void fill2_kernel(
    const int* __restrict__ i0, const int* __restrict__ i1,
    int* cur, int* __restrict__ elist, int N)
{
    int n = blockIdx.x * 256 + threadIdx.x;
    if (n >= N) return;
    int p = atomicAdd(&cur[i0[n]], 1); elist[p] = n;
    p = atomicAdd(&cur[i1[n]], 1);     elist[p] = n;
}

__global__ __launch_bounds__(256) void fill1_kernel(
    const int* __restrict__ idx, const int* __restrict__ payload,
    int* cur, int* __restrict__ elist, int E)
{
    int e = blockIdx.x * 256 + threadIdx.x;
    if (e >= E) return;
    int p = atomicAdd(&cur[idx[e]], 1);
    elist[p] = payload[e];
}

// ---------------- Fused CSR-gather + down MLP ----------------
// h_down[m] = sum over CSR segment of gsrc rows; out[m] = MLP([self[m] | h_down])
__global__ __launch_bounds__(256) void down_csr_kernel(
    const float* __restrict__ self, const float* __restrict__ gsrc,
    const int* __restrict__ start, const int* __restrict__ end,
    const int* __restrict__ elist,
    const float* __restrict__ W1, const float* __restrict__ b1,
    const float* __restrict__ W2, const float* __restrict__ b2,
    float* __restrict__ out, int M)
{
    int m = blockIdx.x * 256 + threadIdx.x;
    if (m >= M) return;
    float hd[NU];
    #pragma unroll
    for (int j = 0; j < NU; j++) hd[j] = 0.f;
    int s = start[m], e = end[m];
    for (int t = s; t < e; ++t) {
        int n = elist[t];
        const float4* g4 = (const float4*)(gsrc + (size_t)n * NU);
        #pragma unroll
        for (int q = 0; q < 8; q++) {
            float4 v = g4[q];
            hd[4*q+0] += v.x; hd[4*q+1] += v.y;
            hd[4*q+2] += v.z; hd[4*q+3] += v.w;
        }
    }
    mlp2_reg(self + (size_t)m * NU, hd, W1, b1, W2, b2, out + (size_t)m * NU);
}

// CSR segment-sum (ring 'h'): out[m] = sum of src rows in segment (0 if empty)
__global__ __launch_bounds__(256) void seg_gather_kernel(
    const float* __restrict__ srcrows, const int* __restrict__ start,
    const int* __restrict__ end, const int* __restrict__ elist,
    float* __restrict__ outrows, int M)
{
    int m = blockIdx.x * 256 + threadIdx.x;
    if (m >= M) return;
    float acc[NU];
    #pragma unroll
    for (int j = 0; j < NU; j++) acc[j] = 0.f;
    int s = start[m], e = end[m];
    for (int t = s; t < e; ++t) {
        int n = elist[t];
        const float4* g4 = (const float4*)(srcrows + (size_t)n * NU);
        #pragma unroll
        for (int q = 0; q < 8; q++) {
            float4 v = g4[q];
            acc[4*q+0] += v.x; acc[4*q+1] += v.y;
            acc[4*q+2] += v.z; acc[4*q+3] += v.w;
        }
    }
    float4* o4 = (float4*)(outrows + (size_t)m * NU);
    #pragma unroll
    for (int q = 0; q < 8; q++)
        o4[q] = make_float4(acc[4*q], acc[4*q+1], acc[4*q+2], acc[4*q+3]);
}

static inline int nblk(int n) { return (n + 255) / 256; }

struct CsrWs { int *start, *cur, *bsums, *elist; };

static void build_csr2(const int* i0, const int* i1, int N, int M,
                       const CsrWs& w, hipStream_t stream)
{
    hipMemsetAsync(w.cur, 0, (size_t)M * sizeof(int), stream);
    hist2_kernel<<<nblk(N), 256, 0, stream>>>(i0, i1, w.cur, N);
    int NB = (M + 1023) / 1024;
    scan1_kernel<<<NB, 256, 0, stream>>>(w.cur, w.start, w.bsums, M);
    scan2_kernel<<<1, 1024, 0, stream>>>(w.bsums, NB);
    scan3_kernel<<<nblk(M), 256, 0, stream>>>(w.start, w.cur, w.bsums, M);
    fill2_kernel<<<nblk(N), 256, 0, stream>>>(i0, i1, w.cur, w.elist, N);
}

static void build_csr1(const int* idx, const int* payload, int E, int M,
                       const CsrWs& w, hipStream_t stream)
{
    hipMemsetAsync(w.cur, 0, (size_t)M * sizeof(int), stream);
    hist1_kernel<<<nblk(E), 256, 0, stream>>>(idx, w.cur, E);
    int NB = (M + 1023) / 1024;
    scan1_kernel<<<NB, 256, 0, stream>>>(w.cur, w.start, w.bsums, M);
    scan2_kernel<<<1, 1024, 0, stream>>>(w.bsums, NB);
    scan3_kernel<<<nblk(M), 256, 0, stream>>>(w.start, w.cur, w.bsums, M);
    fill1_kernel<<<nblk(E), 256, 0, stream>>>(idx, payload, w.cur, w.elist, E);
}

extern "C" void kernel_launch(void* const* d_in, const int* in_sizes, int n_in,
                              void* d_out, int out_size, void* d_ws, size_t ws_size,
                              hipStream_t stream) {
    const float* h1 = (const float*)d_in[0];
    const float* h2 = (const float*)d_in[1];
    const float* h3 = (const float*)d_in[2];
    const float* h4 = (const float*)d_in[3];
    const float* upW1 = (const float*)d_in[4];   // (3,96,32)
    const float* upb1 = (const float*)d_in[5];   // (3,32)
    const float* upW2 = (const float*)d_in[6];   // (3,32,32)
    const float* upb2 = (const float*)d_in[7];   // (3,32)
    const float* dnW1 = (const float*)d_in[8];   // (3,64,32)
    const float* dnb1 = (const float*)d_in[9];
    const float* dnW2 = (const float*)d_in[10];  // (3,32,32)
    const float* dnb2 = (const float*)d_in[11];
    const float* rgW1 = (const float*)d_in[12];  // (64,32)
    const float* rgb1 = (const float*)d_in[13];
    const float* rgW2 = (const float*)d_in[14];  // (32,32)
    const float* rgb2 = (const float*)d_in[15];
    const int* idx2_0 = (const int*)d_in[16];
    const int* idx2_1 = (const int*)d_in[17];
    const int* idx3_0 = (const int*)d_in[18];
    const int* idx3_1 = (const int*)d_in[19];
    const int* idx4_0 = (const int*)d_in[20];
    const int* idx4_1 = (const int*)d_in[21];
    const int* ring_src = (const int*)d_in[22];
    const int* ring_dst = (const int*)d_in[23];

    float* out = (float*)d_out;
    float* o_h1 = out;                                   // 250000*32
    float* o_h2 = out + (size_t)cN1 * NU;                // 500000*32
    float* o_h3 = o_h2 + (size_t)cN2 * NU;               // 1M*32
    float* o_h4 = o_h3 + (size_t)cN3 * NU;               // 1.5M*32
    float* o_hr = o_h4 + (size_t)cN4 * NU;               // 50000*32

    // Workspace: int CSR arenas. Max M = cN3 (1M), max edge-entries = 2*cN4 (3M).
    // Total = 1M + 1M + 1024 + 3M ints = ~20 MB.
    int* wsi = (int*)d_ws;
    CsrWs w;
    w.start = wsi;
    w.cur   = wsi + 1000000;
    w.bsums = wsi + 2000000;
    w.elist = wsi + 2000000 + 1024;

    // ---- up pass (results land in d_out slots; h4 result is final) ----
    up_kernel<<<nblk(cN2), 256, 0, stream>>>(h2, h1, idx2_0, idx2_1,
        upW1 + 0*3072, upb1 + 0*32, upW2 + 0*1024, upb2 + 0*32, o_h2, cN2);
    up_kernel<<<nblk(cN3), 256, 0, stream>>>(h3, o_h2, idx3_0, idx3_1,
        upW1 + 1*3072, upb1 + 1*32, upW2 + 1*1024, upb2 + 1*32, o_h3, cN3);
    up_kernel<<<nblk(cN4), 256, 0, stream>>>(h4, o_h3, idx4_0, idx4_1,
        upW1 + 2*3072, upb1 + 2*32, upW2 + 2*1024, upb2 + 2*32, o_h4, cN4);

    // ---- down i=2 (k=4): CSR over dst in [0,cN3); gather o_h4 rows; MLP in place on o_h3 ----
    build_csr2(idx4_0, idx4_1, cN4, cN3, w, stream);
    down_csr_kernel<<<nblk(cN3), 256, 0, stream>>>(o_h3, o_h4,
        w.start, w.cur, w.elist,
        dnW1 + 2*2048, dnb1 + 2*32, dnW2 + 2*1024, dnb2 + 2*32, o_h3, cN3);

    // ---- down i=1 (k=3) ----
    build_csr2(idx3_0, idx3_1, cN3, cN2, w, stream);
    down_csr_kernel<<<nblk(cN2), 256, 0, stream>>>(o_h2, o_h3,
        w.start, w.cur, w.elist,
        dnW1 + 1*2048, dnb1 + 1*32, dnW2 + 1*1024, dnb2 + 1*32, o_h2, cN2);

    // ---- down i=0 (k=2): self is ORIGINAL h1 input ----
    build_csr2(idx2_0, idx2_1, cN2, cN1, w, stream);
    down_csr_kernel<<<nblk(cN1), 256, 0, stream>>>(h1, o_h2,
        w.start, w.cur, w.elist,
        dnW1 + 0*2048, dnb1 + 0*32, dnW2 + 0*1024, dnb2 + 0*32, o_h1, cN1);

    // ---- ring: h_ring[r] = sum_{e: ring_dst[e]==r} o_h1[ring_src[e]] ----
    // CSR over ring_dst, payload = ring_src (row to gather). Writes all rows (no memset).
    build_csr1(ring_dst, ring_src, cER, cNR, w, stream);
    seg_gather_kernel<<<nblk(cNR), 256, 0, stream>>>(o_h1,
        w.start, w.cur, w.elist, o_hr, cNR);

    // ---- ring down: h_ring_down[i] = sum_{e: ring_src[e]==i} h_ring[ring_dst[e]];
    //      o_h1[i] = MLP([o_h1[i] | h_ring_down[i]])  (in place) ----
    build_csr1(ring_src, ring_dst, cER, cN1, w, stream);
    down_csr_kernel<<<nblk(cN1), 256, 0, stream>>>(o_h1, o_hr,
        w.start, w.cur, w.elist,
        rgW1, rgb1, rgW2, rgb2, o_h1, cN1);
}